// Round 3
// baseline (3086.303 us; speedup 1.0000x reference)
//
#include <hip/hip_runtime.h>
#include <hip/hip_fp16.h>

namespace {

constexpr int NROWS = 256, LSTEPS = 512, IN = 64, LAT = 32, HID = 128;

__device__ __forceinline__ float fast_sigmoid(float x) {
    return __fdividef(1.f, 1.f + __expf(-x));
}
__device__ __forceinline__ float fast_softplus(float x) {
    // log1p(exp(x)), stable form; matches jax.nn.softplus
    return fmaxf(x, 0.f) + log1pf(__expf(-fabsf(x)));
}
__device__ __forceinline__ float fast_tanh(float x) {
    float e = __expf(-2.f * fabsf(x));
    float t = __fdividef(1.f - e, 1.f + e);
    return copysignf(t, x);
}

// Dot of NPAIR f16x2 weight pairs (register-resident) against 2*NPAIR fp32
// activations read from LDS as float4. All weight indices compile-time.
template<int BASE, int NPAIR>
__device__ __forceinline__ float dotp(const float* __restrict__ act, const __half2 (&w)[120]) {
    float acc = 0.f;
#pragma unroll
    for (int i = 0; i < NPAIR / 2; ++i) {
        float4 a = *(const float4*)(act + 4 * i);
        float2 w0 = __half22float2(w[BASE + 2 * i]);
        float2 w1 = __half22float2(w[BASE + 2 * i + 1]);
        acc = fmaf(a.x, w0.x, acc);
        acc = fmaf(a.y, w0.y, acc);
        acc = fmaf(a.z, w1.x, acc);
        acc = fmaf(a.w, w1.y, acc);
    }
    return acc;
}

} // namespace

// One block per batch row n. Threads 0-255 ("X team"): qzcx -> pxcz -> gi.
// Threads 256-511 ("Y team"): gh (only needs h) spread over the same phases,
// plus the gi[256:384) tail. Weights live in per-thread VGPRs as f16 pairs.
__global__ __launch_bounds__(512, 2) void vrnn_kernel(
    const float* __restrict__ X, const float* __restrict__ EZ, const float* __restrict__ EX,
    const float* __restrict__ Wq, const float* __restrict__ bq,
    const float* __restrict__ Wp, const float* __restrict__ bp,
    const float* __restrict__ Wih, const float* __restrict__ Whh,
    const float* __restrict__ bih, const float* __restrict__ bhh,
    float* __restrict__ out)
{
    // Activation buffers laid out so every mat-vec sees a contiguous K range.
    __shared__ alignas(16) float xh[192];   // [ x(64) | h(128) ]   : qzcx input, h for gh
    __shared__ alignas(16) float zh[160];   // [ z(32) | h(128) ]   : pxcz input
    __shared__ alignas(16) float xz[96];    // [ x_gen(64) | z(32) ]: gi input
    __shared__ alignas(16) float q_part[64][4];
    __shared__ alignas(16) float p_part[128][2];
    __shared__ alignas(16) float gi_part[384][2];
    __shared__ alignas(16) float gh_part[384][2];

    const int t = threadIdx.x;
    const int n = blockIdx.x;

    __half2 wpk[120];

    // ---- one-time: load this thread's weight slice into registers (f16x2) ----
    if (t < 256) {
        { // qzcx: out m = t>>2 (64 outs), k-slice ks = t&3 of 48  -> wpk[0..24)
            const int m = t >> 2, k0 = (t & 3) * 48;
#pragma unroll
            for (int j = 0; j < 24; ++j) { int k = k0 + 2 * j;
                wpk[j] = __floats2half2_rn(Wq[k * 64 + m], Wq[(k + 1) * 64 + m]); }
        }
        { // pxcz: out m = t>>1 (128 outs), k-slice ks = t&1 of 80 -> wpk[24..64)
            const int m = t >> 1, k0 = (t & 1) * 80;
#pragma unroll
            for (int j = 0; j < 40; ++j) { int k = k0 + 2 * j;
                wpk[24 + j] = __floats2half2_rn(Wp[k * 128 + m], Wp[(k + 1) * 128 + m]); }
        }
        { // gi outs 0..255 full K=96 -> wpk[64..112)
            const int m = t;
#pragma unroll
            for (int j = 0; j < 48; ++j) { int k = 2 * j;
                wpk[64 + j] = __floats2half2_rn(Wih[k * 384 + m], Wih[(k + 1) * 384 + m]); }
        }
    } else {
        const int y = t - 256;
        const int mo = y >> 1, k0 = (y & 1) * 64;
#pragma unroll
        for (int s = 0; s < 3; ++s) { // gh: 384 outs x 2 K-halves of 64 -> wpk[0..96)
            const int m = s * 128 + mo;
#pragma unroll
            for (int j = 0; j < 32; ++j) { int k = k0 + 2 * j;
                wpk[s * 32 + j] = __floats2half2_rn(Whh[k * 384 + m], Whh[(k + 1) * 384 + m]); }
        }
        { // gi outs 256..383, 2 K-halves of 48 -> wpk[96..120)
            const int m = 256 + mo, kg = (y & 1) * 48;
#pragma unroll
            for (int j = 0; j < 24; ++j) { int k = kg + 2 * j;
                wpk[96 + j] = __floats2half2_rn(Wih[k * 384 + m], Wih[(k + 1) * 384 + m]); }
        }
    }

    // ---- per-role bias registers ----
    float bz0 = 0.f, bz1 = 0.f, bx0 = 0.f, bx1 = 0.f;
    float bir = 0.f, biz = 0.f, bin_ = 0.f, bhr = 0.f, bhz = 0.f, bhn = 0.f;
    if (t < 32)  { bz0 = bq[t]; bz1 = bq[t + 32]; }
    if (t < 64)  { bx0 = bp[t]; bx1 = bp[t + 64]; }
    if (t < 128) { bir = bih[t]; biz = bih[128 + t]; bin_ = bih[256 + t];
                   bhr = bhh[t]; bhz = bhh[128 + t]; bhn = bhh[256 + t]; }

    // ---- prologue: h = 0, stage step-0 inputs ----
    const float* Xrow = X + n * (LSTEPS * IN);
    float* orow = out + n * (LSTEPS * HID);
    if (t < 128) { xh[64 + t] = 0.f; zh[32 + t] = 0.f; }
    if (t < 64)  xh[t] = Xrow[t];
    float ez_nxt = (t < 32) ? EZ[n * LAT + t] : 0.f;   // eps_z[0,0,n,t]
    float ex_nxt = (t < 64) ? EX[n * IN + t]  : 0.f;   // eps_x[0,0,n,t]
    float xn_nxt = 0.f;
    __syncthreads();

    for (int l = 0; l < LSTEPS; ++l) {
        const float ez_cur = ez_nxt, ex_cur = ex_nxt;
        if (l + 1 < LSTEPS) { // prefetch next step's per-thread globals
            if (t < 32) ez_nxt = EZ[(l + 1) * (NROWS * LAT) + n * LAT + t];
            if (t < 64) { ex_nxt = EX[(l + 1) * (NROWS * IN) + n * IN + t];
                          xn_nxt = Xrow[(l + 1) * IN + t]; }
        }

        // Phase A: qzcx partials (X) || gh outs 0..127 (Y)
        if (t < 256) {
            const int m = t >> 2, ks = t & 3;
            q_part[m][ks] = dotp<0, 24>(xh + ks * 48, wpk);
        } else {
            const int y = t - 256;
            gh_part[y >> 1][y & 1] = dotp<0, 32>(xh + 64 + (y & 1) * 64, wpk);
        }
        __syncthreads();

        // Z: reduce q, rsample z_gen
        if (t < 32) {
            float mean = q_part[t][0] + q_part[t][1] + q_part[t][2] + q_part[t][3] + bz0;
            float raw  = q_part[t + 32][0] + q_part[t + 32][1] + q_part[t + 32][2] + q_part[t + 32][3] + bz1;
            float z = fmaf(fast_softplus(raw), ez_cur, mean);
            zh[t] = z; xz[64 + t] = z;
        }
        __syncthreads();

        // Phase B: pxcz partials (X) || gh outs 128..255 (Y)
        if (t < 256) {
            const int m = t >> 1, ks = t & 1;
            p_part[m][ks] = dotp<24, 40>(zh + ks * 80, wpk);
        } else {
            const int y = t - 256;
            gh_part[128 + (y >> 1)][y & 1] = dotp<32, 32>(xh + 64 + (y & 1) * 64, wpk);
        }
        __syncthreads();

        // XG: reduce p, rsample x_gen
        if (t < 64) {
            float mean = p_part[t][0] + p_part[t][1] + bx0;
            float raw  = p_part[t + 64][0] + p_part[t + 64][1] + bx1;
            xz[t] = fmaf(fast_softplus(raw), ex_cur, mean);
        }
        __syncthreads();

        // Phase D: gi outs 0..255 (X, also refresh next x) || gh outs 256..383 + gi tail (Y)
        if (t < 256) {
            gi_part[t][0] = dotp<64, 48>(xz, wpk);
            if (t < 64 && l + 1 < LSTEPS) xh[t] = xn_nxt;
        } else {
            const int y = t - 256;
            gh_part[256 + (y >> 1)][y & 1] = dotp<64, 32>(xh + 64 + (y & 1) * 64, wpk);
            gi_part[256 + (y >> 1)][y & 1] = dotp<96, 24>(xz + (y & 1) * 48, wpk);
        }
        __syncthreads();

        // Gates: GRU update, write h and global output
        if (t < 128) {
            float gir = gi_part[t][0] + bir;
            float giz = gi_part[128 + t][0] + biz;
            float gin = gi_part[256 + t][0] + gi_part[256 + t][1] + bin_;
            float ghr = gh_part[t][0] + gh_part[t][1] + bhr;
            float ghz = gh_part[128 + t][0] + gh_part[128 + t][1] + bhz;
            float ghn = gh_part[256 + t][0] + gh_part[256 + t][1] + bhn;
            float r  = fast_sigmoid(gir + ghr);
            float zg = fast_sigmoid(giz + ghz);
            float nn = fast_tanh(fmaf(r, ghn, gin));
            float hprev = xh[64 + t];
            float hnew = fmaf(zg, hprev - nn, nn);   // (1-z)*n + z*h
            xh[64 + t] = hnew; zh[32 + t] = hnew;
            orow[l * HID + t] = hnew;
        }
        __syncthreads();
    }

    // hs_final[0, n, :]
    if (t < 128) out[NROWS * LSTEPS * HID + n * HID + t] = xh[64 + t];
}

extern "C" void kernel_launch(void* const* d_in, const int* in_sizes, int n_in,
                              void* d_out, int out_size, void* d_ws, size_t ws_size,
                              hipStream_t stream) {
    const float* X   = (const float*)d_in[0];
    const float* EZ  = (const float*)d_in[1];
    const float* EX  = (const float*)d_in[2];
    const float* Wq  = (const float*)d_in[3];
    const float* bq  = (const float*)d_in[4];
    const float* Wp  = (const float*)d_in[5];
    const float* bp  = (const float*)d_in[6];
    const float* Wih = (const float*)d_in[7];
    const float* Whh = (const float*)d_in[8];
    const float* bih = (const float*)d_in[9];
    const float* bhh = (const float*)d_in[10];
    float* out = (float*)d_out;

    vrnn_kernel<<<dim3(NROWS), dim3(512), 0, stream>>>(
        X, EZ, EX, Wq, bq, Wp, bp, Wih, Whh, bih, bhh, out);
}

// Round 4
// 952.141 us; speedup vs baseline: 3.2414x; 3.2414x over previous
//
#include <hip/hip_runtime.h>

namespace {

constexpr int NROWS = 256, LSTEPS = 512, IN = 64, LAT = 32, HID = 128;

typedef _Float16 h2 __attribute__((ext_vector_type(2)));
typedef _Float16 h8 __attribute__((ext_vector_type(8)));

__device__ __forceinline__ float fast_sigmoid(float x) {
    return __fdividef(1.f, 1.f + __expf(-x));
}
__device__ __forceinline__ float fast_softplus(float x) {
    return fmaxf(x, 0.f) + log1pf(__expf(-fabsf(x)));
}
__device__ __forceinline__ float fast_tanh(float x) {
    float e = __expf(-2.f * fabsf(x));
    float t = __fdividef(1.f - e, 1.f + e);
    return copysignf(t, x);
}

__device__ __forceinline__ float dot2f(h2 w, h2 a, float c) {
#if __has_builtin(__builtin_amdgcn_fdot2)
    return __builtin_amdgcn_fdot2(w, a, c, false);
#else
    return fmaf((float)w[0], (float)a[0], fmaf((float)w[1], (float)a[1], c));
#endif
}

__device__ __forceinline__ h2 packw(float a, float b) {
    h2 r; r[0] = (_Float16)a; r[1] = (_Float16)b; return r;
}

// Dot of NPAIR register-resident f16x2 weight pairs against 2*NPAIR f16
// activations in LDS (read as 16B blocks). 4 split accumulators break the
// dependency chain. NPAIR must be a multiple of 4; act 16B-aligned.
template<int BASE, int NPAIR>
__device__ __forceinline__ float dotp2(const _Float16* act, const h2 (&w)[120]) {
    float a0 = 0.f, a1 = 0.f, a2 = 0.f, a3 = 0.f;
#pragma unroll
    for (int i = 0; i < NPAIR / 4; ++i) {
        h8 blk = *(const h8*)(act + 8 * i);
        a0 = dot2f(w[BASE + 4 * i + 0], __builtin_shufflevector(blk, blk, 0, 1), a0);
        a1 = dot2f(w[BASE + 4 * i + 1], __builtin_shufflevector(blk, blk, 2, 3), a1);
        a2 = dot2f(w[BASE + 4 * i + 2], __builtin_shufflevector(blk, blk, 4, 5), a2);
        a3 = dot2f(w[BASE + 4 * i + 3], __builtin_shufflevector(blk, blk, 6, 7), a3);
    }
    return (a0 + a1) + (a2 + a3);
}

} // namespace

// One block per batch row n. Threads 0-255 ("X team"): qzcx -> pxcz -> gi.
// Threads 256-511 ("Y team"): gh (only needs h) spread over the same phases,
// plus the gi[256:384) tail. Weights live in per-thread VGPRs as f16 pairs;
// activations cross phases through LDS as f16; GRU state h stays f32 in the
// owning thread's register. waves_per_eu(2,2) pins the 256-VGPR budget.
__global__ __launch_bounds__(512)
__attribute__((amdgpu_waves_per_eu(2, 2)))
void vrnn_kernel(
    const float* __restrict__ X, const float* __restrict__ EZ, const float* __restrict__ EX,
    const float* __restrict__ Wq, const float* __restrict__ bq,
    const float* __restrict__ Wp, const float* __restrict__ bp,
    const float* __restrict__ Wih, const float* __restrict__ Whh,
    const float* __restrict__ bih, const float* __restrict__ bhh,
    float* __restrict__ out)
{
    // f16 activation buffers, each a contiguous K-range for its mat-vec.
    __shared__ alignas(16) _Float16 XH[192];  // [ x(64) | h(128) ] : qzcx input, h for gh
    __shared__ alignas(16) _Float16 ZH[160];  // [ z(32) | h(128) ] : pxcz input
    __shared__ alignas(16) _Float16 XZ[96];   // [ x_gen(64) | z(32) ]: gi input
    __shared__ alignas(16) float q_part[64][4];
    __shared__ alignas(16) float p_part[128][2];
    __shared__ alignas(16) float gi_part[384][2];
    __shared__ alignas(16) float gh_part[384][2];

    const int t = threadIdx.x;
    const int n = blockIdx.x;

    h2 wpk[120];

    // ---- one-time: load this thread's weight slice into registers (f16x2) ----
    if (t < 256) {
        { // qzcx: out m = t>>2 (64 outs), k-slice ks = t&3 of 24 pairs -> wpk[0..24)
            const int m = t >> 2, k0 = (t & 3) * 48;
#pragma unroll
            for (int j = 0; j < 24; ++j) { int k = k0 + 2 * j;
                wpk[j] = packw(Wq[k * 64 + m], Wq[(k + 1) * 64 + m]); }
        }
        { // pxcz: out m = t>>1 (128 outs), k-slice ks = t&1 of 40 pairs -> wpk[24..64)
            const int m = t >> 1, k0 = (t & 1) * 80;
#pragma unroll
            for (int j = 0; j < 40; ++j) { int k = k0 + 2 * j;
                wpk[24 + j] = packw(Wp[k * 128 + m], Wp[(k + 1) * 128 + m]); }
        }
        { // gi outs 0..255 full K=96 (48 pairs) -> wpk[64..112)
            const int m = t;
#pragma unroll
            for (int j = 0; j < 48; ++j) { int k = 2 * j;
                wpk[64 + j] = packw(Wih[k * 384 + m], Wih[(k + 1) * 384 + m]); }
        }
    } else {
        const int y = t - 256;
        const int mo = y >> 1, k0 = (y & 1) * 64;
#pragma unroll
        for (int s = 0; s < 3; ++s) { // gh: 384 outs x 2 K-halves of 32 pairs -> wpk[0..96)
            const int m = s * 128 + mo;
#pragma unroll
            for (int j = 0; j < 32; ++j) { int k = k0 + 2 * j;
                wpk[s * 32 + j] = packw(Whh[k * 384 + m], Whh[(k + 1) * 384 + m]); }
        }
        { // gi outs 256..383, 2 K-halves of 24 pairs -> wpk[96..120)
            const int m = 256 + mo, kg = (y & 1) * 48;
#pragma unroll
            for (int j = 0; j < 24; ++j) { int k = kg + 2 * j;
                wpk[96 + j] = packw(Wih[k * 384 + m], Wih[(k + 1) * 384 + m]); }
        }
    }

    // ---- per-role bias registers ----
    float bz0 = 0.f, bz1 = 0.f, bx0 = 0.f, bx1 = 0.f;
    float bir = 0.f, biz = 0.f, bin_ = 0.f, bhr = 0.f, bhz = 0.f, bhn = 0.f;
    if (t < 32)  { bz0 = bq[t]; bz1 = bq[t + 32]; }
    if (t < 64)  { bx0 = bp[t]; bx1 = bp[t + 64]; }
    if (t < 128) { bir = bih[t]; biz = bih[128 + t]; bin_ = bih[256 + t];
                   bhr = bhh[t]; bhz = bhh[128 + t]; bhn = bhh[256 + t]; }

    // ---- prologue: h = 0 (reg + LDS), stage step-0 inputs ----
    const float* Xrow = X + n * (LSTEPS * IN);
    float* orow = out + n * (LSTEPS * HID);
    float hreg = 0.f;                           // exact f32 GRU state (t<128 owns h[t])
    if (t < 128) { XH[64 + t] = (_Float16)0.f; ZH[32 + t] = (_Float16)0.f; }
    if (t < 64)  XH[t] = (_Float16)Xrow[t];
    float ez_nxt = (t < 32) ? EZ[n * LAT + t] : 0.f;   // eps_z[0,0,n,t]
    float ex_nxt = (t < 64) ? EX[n * IN + t]  : 0.f;   // eps_x[0,0,n,t]
    float xn_nxt = 0.f;
    __syncthreads();

    for (int l = 0; l < LSTEPS; ++l) {
        const float ez_cur = ez_nxt, ex_cur = ex_nxt;
        if (l + 1 < LSTEPS) { // prefetch next step's per-thread globals
            if (t < 32) ez_nxt = EZ[(l + 1) * (NROWS * LAT) + n * LAT + t];
            if (t < 64) { ex_nxt = EX[(l + 1) * (NROWS * IN) + n * IN + t];
                          xn_nxt = Xrow[(l + 1) * IN + t]; }
        }

        // Phase A: qzcx partials (X) || gh outs 0..127 (Y)
        if (t < 256) {
            const int m = t >> 2, ks = t & 3;
            q_part[m][ks] = dotp2<0, 24>(XH + ks * 48, wpk);
        } else {
            const int y = t - 256;
            gh_part[y >> 1][y & 1] = dotp2<0, 32>(XH + 64 + (y & 1) * 64, wpk);
        }
        __syncthreads();

        // Z: reduce q, rsample z_gen
        if (t < 32) {
            float4 qm = *(const float4*)q_part[t];
            float4 qr = *(const float4*)q_part[t + 32];
            float mean = (qm.x + qm.y) + (qm.z + qm.w) + bz0;
            float raw  = (qr.x + qr.y) + (qr.z + qr.w) + bz1;
            float z = fmaf(fast_softplus(raw), ez_cur, mean);
            ZH[t] = (_Float16)z; XZ[64 + t] = (_Float16)z;
        }
        __syncthreads();

        // Phase B: pxcz partials (X) || gh outs 128..255 (Y)
        if (t < 256) {
            const int m = t >> 1, ks = t & 1;
            p_part[m][ks] = dotp2<24, 40>(ZH + ks * 80, wpk);
        } else {
            const int y = t - 256;
            gh_part[128 + (y >> 1)][y & 1] = dotp2<32, 32>(XH + 64 + (y & 1) * 64, wpk);
        }
        __syncthreads();

        // XG: reduce p, rsample x_gen
        if (t < 64) {
            float mean = p_part[t][0] + p_part[t][1] + bx0;
            float raw  = p_part[t + 64][0] + p_part[t + 64][1] + bx1;
            float xg = fmaf(fast_softplus(raw), ex_cur, mean);
            XZ[t] = (_Float16)xg;
        }
        __syncthreads();

        // Phase D: gi outs 0..255 (X, + refresh next x) || gh outs 256..383 + gi tail (Y)
        if (t < 256) {
            gi_part[t][0] = dotp2<64, 48>(XZ, wpk);
            if (t < 64 && l + 1 < LSTEPS) XH[t] = (_Float16)xn_nxt;
        } else {
            const int y = t - 256;
            gh_part[256 + (y >> 1)][y & 1] = dotp2<64, 32>(XH + 64 + (y & 1) * 64, wpk);
            gi_part[256 + (y >> 1)][y & 1] = dotp2<96, 24>(XZ + (y & 1) * 48, wpk);
        }
        __syncthreads();

        // Gates: GRU update; h state stays f32 in hreg, f16 copies go to LDS
        if (t < 128) {
            float gir = gi_part[t][0] + bir;
            float giz = gi_part[128 + t][0] + biz;
            float gin = gi_part[256 + t][0] + gi_part[256 + t][1] + bin_;
            float ghr = gh_part[t][0] + gh_part[t][1] + bhr;
            float ghz = gh_part[128 + t][0] + gh_part[128 + t][1] + bhz;
            float ghn = gh_part[256 + t][0] + gh_part[256 + t][1] + bhn;
            float r  = fast_sigmoid(gir + ghr);
            float zg = fast_sigmoid(giz + ghz);
            float nn = fast_tanh(fmaf(r, ghn, gin));
            float hnew = fmaf(zg, hreg - nn, nn);   // (1-z)*n + z*h
            hreg = hnew;
            _Float16 hf = (_Float16)hnew;
            XH[64 + t] = hf; ZH[32 + t] = hf;
            orow[l * HID + t] = hnew;
        }
        __syncthreads();
    }

    // hs_final[0, n, :]
    if (t < 128) out[NROWS * LSTEPS * HID + n * HID + t] = hreg;
}

extern "C" void kernel_launch(void* const* d_in, const int* in_sizes, int n_in,
                              void* d_out, int out_size, void* d_ws, size_t ws_size,
                              hipStream_t stream) {
    const float* X   = (const float*)d_in[0];
    const float* EZ  = (const float*)d_in[1];
    const float* EX  = (const float*)d_in[2];
    const float* Wq  = (const float*)d_in[3];
    const float* bq  = (const float*)d_in[4];
    const float* Wp  = (const float*)d_in[5];
    const float* bp  = (const float*)d_in[6];
    const float* Wih = (const float*)d_in[7];
    const float* Whh = (const float*)d_in[8];
    const float* bih = (const float*)d_in[9];
    const float* bhh = (const float*)d_in[10];
    float* out = (float*)d_out;

    vrnn_kernel<<<dim3(NROWS), dim3(512), 0, stream>>>(
        X, EZ, EX, Wq, bq, Wp, bp, Wih, Whh, bih, bhh, out);
}